// Round 8
// baseline (175.798 us; speedup 1.0000x reference)
//
#include <hip/hip_runtime.h>
#include <hip/hip_bf16.h>
#include <math.h>

// Z = Q_F (D * (Q_F^T X Q_S)) Q_S^T  ==  per-column solve (I - g*lam_j*G) y_j = (X Q_S)_j ; Z = Y Q_S^T
// (I - aG)^-1 = prod_{j=0..4} (I + a^(2^j) G^(2^j))  (exact 31-term Neumann sum; rho <= 0.76)
// Round 8: LDS-free, barrier-free GEMMs. Each wave owns a 32x32 tile; MFMA fragments are
// built directly from global loads (operand-layout addressing), packed bf16 cvt in-register.
// A = RNE hi/lo split (2 products, ~2^-17 rel), B = RNE bf16 (2^-9 rel). fp32 atomics epilogue.

typedef short short8 __attribute__((ext_vector_type(8)));
typedef float floatx16 __attribute__((ext_vector_type(16)));

#define KSPLIT 16
#define KCHUNK 256  // 4096 / KSPLIT; 16 k16-iterations
constexpr int Mdim = 64;
constexpr int Ndim = 4096;

__device__ inline ushort f2bf(float f) {
    uint u = __float_as_uint(f);
    u += 0x7fff + ((u >> 16) & 1);  // RNE
    return (ushort)(u >> 16);
}
__device__ inline float bf2f(ushort h) { return __uint_as_float(((uint)h) << 16); }

__device__ inline floatx16 mfma_bf16(short8 a, short8 b, floatx16 c) {
    return __builtin_amdgcn_mfma_f32_32x32x16_bf16(a, b, c, 0, 0, 0);
}

union U8 { short8 v; ushort2 p[4]; };

// packed RNE f32x2 -> bf16x2 (v_cvt_pk_bf16_f32)
__device__ inline ushort2 pk_bf16(float a, float b) {
    float2 f; f.x = a; f.y = b;
    __hip_bfloat162 h = __float22bfloat162_rn(f);
    return *(ushort2*)&h;
}

// hi/lo split of a float pair: h = rne_bf16(f), lo = rne_bf16(f - h)  (Sterbenz: f-h exact)
__device__ inline void split_pair(float f0, float f1, ushort2& h, ushort2& lo) {
    h = pk_bf16(f0, f1);
    uint hp = *(uint*)&h;
    float g0 = __uint_as_float(hp << 16);
    float g1 = __uint_as_float(hp & 0xffff0000u);
    lo = pk_bf16(f0 - g0, f1 - g1);
}

struct SharedPrep { float Fraw[64 * 65]; ushort Ph[4096], Pl[4096]; float red[256]; };

// ---------------- init: zero W (ws) and Z (d_out) ----------------------------
__global__ __launch_bounds__(256) void init_kernel(float* __restrict__ W, float* __restrict__ Z) {
    const int i = blockIdx.x * 256 + threadIdx.x;
    float4 z = {0.f, 0.f, 0.f, 0.f};
    if (i < 65536) *(float4*)&W[i * 4] = z;
    else *(float4*)&Z[(i - 65536) * 4] = z;
}

// ---------------- prep body: G, G^2, G^4, G^8, G^16 (one block) -------------
__device__ void prep_body(SharedPrep& sp, const float* __restrict__ F, float* __restrict__ Gout) {
    const int t = threadIdx.x;
    const int l = t & 63, w = t >> 6;
    const int tm = w & 1, tn = w >> 1;
    const int am = tm * 32 + (l & 31);
    const int bn = tn * 32 + (l & 31);
    const int lk = l >> 5;

    for (int s = 0; s < 4; ++s) {
        int e = t + 256 * s;
        int r = e >> 4, q = (e & 15) * 4;
        float4 v = *(const float4*)&F[r * 64 + q];
        float fa[4] = {v.x, v.y, v.z, v.w};
        for (int i = 0; i < 4; ++i) sp.Fraw[r * 65 + q + i] = fa[i];
    }
    __syncthreads();
    {  // transpose into planes: P[c][k] = F[k][c]
        int c = t >> 2, kbase = (t & 3) * 16;
        ushort hh[16], ll[16];
#pragma unroll
        for (int kk = 0; kk < 16; ++kk) {
            float v = sp.Fraw[(kbase + kk) * 65 + c];
            ushort h = f2bf(v);
            hh[kk] = h;
            ll[kk] = f2bf(v - bf2f(h));
        }
#pragma unroll
        for (int g = 0; g < 2; ++g) {
            int gk = (kbase >> 3) + g;
            int idx = c * 64 + ((gk ^ (c & 7)) * 8);
#pragma unroll
            for (int u = 0; u < 8; ++u) { sp.Ph[idx + u] = hh[8 * g + u]; sp.Pl[idx + u] = ll[8 * g + u]; }
        }
    }
    __syncthreads();
    floatx16 acc;
    for (int i = 0; i < 16; ++i) acc[i] = 0.f;
    for (int s16 = 0; s16 < 4; ++s16) {
        int gk = 2 * s16 + lk;
        int ai = am * 64 + ((gk ^ (am & 7)) * 8);
        int bi = bn * 64 + ((gk ^ (bn & 7)) * 8);
        short8 ah = *(const short8*)&sp.Ph[ai];
        short8 al = *(const short8*)&sp.Pl[ai];
        short8 bh = *(const short8*)&sp.Ph[bi];
        short8 bl = *(const short8*)&sp.Pl[bi];
        acc = mfma_bf16(ah, bh, acc);
        acc = mfma_bf16(al, bh, acc);
        acc = mfma_bf16(ah, bl, acc);
    }
    float ss = 0.f;
    for (int r = 0; r < 16; ++r) ss += acc[r] * acc[r];
    sp.red[t] = ss;
    __syncthreads();
    for (int off = 128; off > 0; off >>= 1) {
        if (t < off) sp.red[t] += sp.red[t + off];
        __syncthreads();
    }
    const float inv = 1.0f / (sqrtf(sp.red[0]) + 1e-12f);
    for (int r = 0; r < 16; ++r) {
        int row = (r & 3) + 8 * (r >> 2) + 4 * lk + tm * 32;
        int col = tn * 32 + (l & 31);
        float v = acc[r] * inv;
        Gout[row * 64 + col] = v;
        ushort h = f2bf(v);
        int idx = row * 64 + (((col >> 3) ^ (row & 7)) * 8 + (col & 7));
        sp.Ph[idx] = h;
        sp.Pl[idx] = f2bf(v - bf2f(h));
    }
    for (int j = 1; j < 5; ++j) {
        __syncthreads();
        floatx16 a2;
        for (int i = 0; i < 16; ++i) a2[i] = 0.f;
        for (int s16 = 0; s16 < 4; ++s16) {
            int gk = 2 * s16 + lk;
            int ai = am * 64 + ((gk ^ (am & 7)) * 8);
            int bi = bn * 64 + ((gk ^ (bn & 7)) * 8);
            short8 ah = *(const short8*)&sp.Ph[ai];
            short8 al = *(const short8*)&sp.Pl[ai];
            short8 bh = *(const short8*)&sp.Ph[bi];
            short8 bl = *(const short8*)&sp.Pl[bi];
            a2 = mfma_bf16(ah, bh, a2);
            a2 = mfma_bf16(al, bh, a2);
            a2 = mfma_bf16(ah, bl, a2);
        }
        __syncthreads();
        for (int r = 0; r < 16; ++r) {
            int row = (r & 3) + 8 * (r >> 2) + 4 * lk + tm * 32;
            int col = tn * 32 + (l & 31);
            float v = a2[r];
            Gout[j * 4096 + row * 64 + col] = v;
            ushort h = f2bf(v);
            int idx = row * 64 + (((col >> 3) ^ (row & 7)) * 8 + (col & 7));
            sp.Ph[idx] = h;
            sp.Pl[idx] = f2bf(v - bf2f(h));
        }
    }
}

// ---------------- gemm1: W += X @ Qs-chunk  (LDS-free; block 0 = prep) ------
// A-frag: lane reads X[row=tm*32+(l&31)][k..k+7] contiguous.
// B-frag: lane reads Qs[k + (l>>5)*8 + j][col] (coalesced across lanes, j=0..7).
__global__ __launch_bounds__(256, 4) void gemm1_kernel(const float* __restrict__ X,
                                                       const float* __restrict__ Qs,
                                                       float* __restrict__ W,
                                                       const float* __restrict__ F,
                                                       float* __restrict__ Gp) {
    __shared__ SharedPrep sp;  // used only by block 0
    const int bid = blockIdx.x;
    if (bid == 0) { prep_body(sp, F, Gp); return; }
    const int b = bid - 1;
    const int n0 = (b & 63) * 64;
    const int kb = (b >> 6) * KCHUNK;
    const int t = threadIdx.x;
    const int l = t & 63, w = t >> 6;
    const int tm = w & 1, tn = w >> 1;
    const int arow = tm * 32 + (l & 31);
    const int bcol = n0 + tn * 32 + (l & 31);
    const int lk8 = (l >> 5) * 8;
    const float* Arow = X + (size_t)arow * 4096;
    const float* Bcol = Qs + bcol;

    floatx16 acc;
    for (int i = 0; i < 16; ++i) acc[i] = 0.f;

#pragma unroll 2
    for (int it = 0; it < KCHUNK / 16; ++it) {
        const int k0 = kb + it * 16 + lk8;
        float4 a0 = *(const float4*)&Arow[k0];
        float4 a1 = *(const float4*)&Arow[k0 + 4];
        float bw[8];
#pragma unroll
        for (int j = 0; j < 8; ++j) bw[j] = Bcol[(size_t)(k0 + j) * 4096];
        U8 ah, al, bh;
        split_pair(a0.x, a0.y, ah.p[0], al.p[0]);
        split_pair(a0.z, a0.w, ah.p[1], al.p[1]);
        split_pair(a1.x, a1.y, ah.p[2], al.p[2]);
        split_pair(a1.z, a1.w, ah.p[3], al.p[3]);
#pragma unroll
        for (int j = 0; j < 4; ++j) bh.p[j] = pk_bf16(bw[2 * j], bw[2 * j + 1]);
        acc = mfma_bf16(ah.v, bh.v, acc);
        acc = mfma_bf16(al.v, bh.v, acc);
    }
#pragma unroll
    for (int r = 0; r < 16; ++r) {
        const int orow = (r & 3) + 8 * (r >> 2) + 4 * (l >> 5) + tm * 32;
        atomicAdd(&W[orow * 4096 + bcol], acc[r]);
    }
}

// ---------------- gemm2: Z += Y @ Qs^T  (LDS-free) ---------------------------
// B-frag: lane reads Qs[col][k..k+7] contiguous (row-major n,k == Qs^T's B layout).
__global__ __launch_bounds__(256, 4) void gemm2_kernel(const float* __restrict__ Y,
                                                       const float* __restrict__ Qs,
                                                       float* __restrict__ Z) {
    const int b = blockIdx.x;
    const int n0 = (b & 63) * 64;
    const int kb = (b >> 6) * KCHUNK;
    const int t = threadIdx.x;
    const int l = t & 63, w = t >> 6;
    const int tm = w & 1, tn = w >> 1;
    const int arow = tm * 32 + (l & 31);
    const int bcol = n0 + tn * 32 + (l & 31);
    const int lk8 = (l >> 5) * 8;
    const float* Arow = Y + (size_t)arow * 4096;
    const float* Brow = Qs + (size_t)bcol * 4096;

    floatx16 acc;
    for (int i = 0; i < 16; ++i) acc[i] = 0.f;

#pragma unroll 2
    for (int it = 0; it < KCHUNK / 16; ++it) {
        const int k0 = kb + it * 16 + lk8;
        float4 a0 = *(const float4*)&Arow[k0];
        float4 a1 = *(const float4*)&Arow[k0 + 4];
        float4 b0 = *(const float4*)&Brow[k0];
        float4 b1 = *(const float4*)&Brow[k0 + 4];
        U8 ah, al, bh;
        split_pair(a0.x, a0.y, ah.p[0], al.p[0]);
        split_pair(a0.z, a0.w, ah.p[1], al.p[1]);
        split_pair(a1.x, a1.y, ah.p[2], al.p[2]);
        split_pair(a1.z, a1.w, ah.p[3], al.p[3]);
        bh.p[0] = pk_bf16(b0.x, b0.y);
        bh.p[1] = pk_bf16(b0.z, b0.w);
        bh.p[2] = pk_bf16(b1.x, b1.y);
        bh.p[3] = pk_bf16(b1.z, b1.w);
        acc = mfma_bf16(ah.v, bh.v, acc);
        acc = mfma_bf16(al.v, bh.v, acc);
    }
#pragma unroll
    for (int r = 0; r < 16; ++r) {
        const int orow = (r & 3) + 8 * (r >> 2) + 4 * (l >> 5) + tm * 32;
        atomicAdd(&Z[orow * 4096 + bcol], acc[r]);
    }
}

// ---------------- solve: T += a^(2^j) * (G_j @ T), j=0..4 -------------------
__global__ __launch_bounds__(256) void solve_kernel(const float* __restrict__ W,
                                                    const float* __restrict__ Gp,
                                                    const float* __restrict__ lam,
                                                    const float* __restrict__ gammap,
                                                    float* __restrict__ Y) {
    __shared__ float Gs[64][68];
    __shared__ float T[64][17];
    const int t = threadIdx.x;
    const int c0 = blockIdx.x * 16;
    for (int e = t; e < 1024; e += 256)
        T[e >> 4][e & 15] = W[(e >> 4) * 4096 + c0 + (e & 15)];
    const int tx = t & 15;
    const int r4 = (t >> 4) * 4;
    const float a = gammap[0] * lam[c0 + tx];
    float s = a;
    for (int j = 0; j < 5; ++j) {
        __syncthreads();
        for (int e = t; e < 4096; e += 256) Gs[e >> 6][e & 63] = Gp[j * 4096 + e];
        __syncthreads();
        float u0 = 0.f, u1 = 0.f, u2 = 0.f, u3 = 0.f;
#pragma unroll 8
        for (int k = 0; k < 64; ++k) {
            const float tv = T[k][tx];
            const float4 g = *(const float4*)&Gs[k][r4];
            u0 += g.x * tv; u1 += g.y * tv; u2 += g.z * tv; u3 += g.w * tv;
        }
        __syncthreads();
        T[r4 + 0][tx] += s * u0;
        T[r4 + 1][tx] += s * u1;
        T[r4 + 2][tx] += s * u2;
        T[r4 + 3][tx] += s * u3;
        s = s * s;
    }
    __syncthreads();
    for (int e = t; e < 1024; e += 256)
        Y[(e >> 4) * 4096 + c0 + (e & 15)] = T[e >> 4][e & 15];
}

extern "C" void kernel_launch(void* const* d_in, const int* in_sizes, int n_in,
                              void* d_out, int out_size, void* d_ws, size_t ws_size,
                              hipStream_t stream) {
    const float* X     = (const float*)d_in[0];
    const float* F     = (const float*)d_in[1];
    const float* Qs    = (const float*)d_in[2];
    const float* lam   = (const float*)d_in[3];
    const float* gamma = (const float*)d_in[4];
    float* Z = (float*)d_out;

    float* W  = (float*)d_ws;       // 64*4096 f (1 MB)
    float* Y  = W + Mdim * Ndim;    // 1 MB
    float* Gp = Y + Mdim * Ndim;    // 5*4096 f

    init_kernel<<<512, 256, 0, stream>>>(W, Z);
    gemm1_kernel<<<64 * KSPLIT + 1, 256, 0, stream>>>(X, Qs, W, F, Gp);
    solve_kernel<<<Ndim / 16, 256, 0, stream>>>(W, Gp, lam, gamma, Y);
    gemm2_kernel<<<64 * KSPLIT, 256, 0, stream>>>(Y, Qs, Z);
}